// Round 10
// baseline (546.841 us; speedup 1.0000x reference)
//
#include <hip/hip_runtime.h>
#include <hip/hip_bf16.h>
#include <stdint.h>

#define B_ 128
#define C_ 512
#define H_ 8
#define W_ 64
#define L_ 512
#define EMB_ 512
#define HID_ 512
#define M_ 65536
#define PH 10
#define PW 66
#define PADSZ (B_*PH*PW*C_)     /* bf16 elements */
#define BT_SZ (9*EMB_*C_)       /* bf16 elements */
#define GEM_SZ (B_*EMB_)        /* f32 */

typedef __attribute__((ext_vector_type(8))) short short8;
typedef __attribute__((ext_vector_type(4))) float f32x4;
typedef __attribute__((ext_vector_type(16))) float f32x16;

__device__ __forceinline__ void gload16(const void* g, void* l) {
    __builtin_amdgcn_global_load_lds(
        (const __attribute__((address_space(1))) unsigned int*)g,
        (__attribute__((address_space(3))) unsigned int*)l, 16, 0, 0);
}

__device__ __forceinline__ float fast_tanh(float x) {
    float e = __expf(2.0f * fabsf(x));
    float r = 1.0f - __fdividef(2.0f, e + 1.0f);
    return copysignf(r, x);
}

// ---- pad + transpose conv_f -> padded channel-last bf16 [B][PH][PW][C]; zeroes own halo
__global__ __launch_bounds__(256) void k_pad(const float* __restrict__ cf,
                                             __hip_bfloat16* __restrict__ pad) {
    int bid = blockIdx.x, t = threadIdx.x;
    int b = bid >> 3, y = bid & 7;
    for (int cc = 0; cc < 2; ++cc) {
        int c = cc * 256 + t;
        const float* src = cf + ((size_t)(b * C_ + c) * H_ + y) * W_;
        __hip_bfloat16* dst = pad + ((size_t)(b * PH + y + 1) * PW + 1) * C_ + c;
#pragma unroll
        for (int x = 0; x < W_; ++x)
            dst[(size_t)x * C_] = __float2bfloat16(src[x]);
    }
    // halo cols x=0, x=65 of row y+1
    __hip_bfloat16 z = __float2bfloat16(0.0f);
    for (int c = t; c < C_; c += 256) {
        pad[((size_t)(b * PH + y + 1) * PW + 0) * C_ + c] = z;
        pad[((size_t)(b * PH + y + 1) * PW + 65) * C_ + c] = z;
    }
    // halo rows 0 and 9 (uint stores, 2 bf16 each)
    if (y == 0) {
        unsigned int* r0 = (unsigned int*)(pad + (size_t)(b * PH + 0) * PW * C_);
        for (int i = t; i < PW * C_ / 2; i += 256) r0[i] = 0u;
    }
    if (y == 7) {
        unsigned int* r9 = (unsigned int*)(pad + (size_t)(b * PH + 9) * PW * C_);
        for (int i = t; i < PW * C_ / 2; i += 256) r9[i] = 0u;
    }
}

// ---- K_conv [EMB,C,3,3] f32 -> Bt [tap][e][c] bf16
__global__ __launch_bounds__(256) void k_wt(const float* __restrict__ kc,
                                            __hip_bfloat16* __restrict__ bt) {
    int e = blockIdx.x, t = threadIdx.x;
    for (int cc = 0; cc < 2; ++cc) {
        int c = cc * 256 + t;
        const float* src = kc + (size_t)(e * C_ + c) * 9;
#pragma unroll
        for (int tap = 0; tap < 9; ++tap)
            bt[(size_t)tap * EMB_ * C_ + e * C_ + c] = __float2bfloat16(src[tap]);
    }
}

// ---- g_em = h @ W_h^T + b_h (fp32), 1024 blocks, 4 threads per output
__global__ __launch_bounds__(256) void k_gem(const float* __restrict__ h,
                                             const float* __restrict__ Wh,
                                             const float* __restrict__ bh,
                                             float* __restrict__ gem) {
    int bid = blockIdx.x, t = threadIdx.x;
    int b = bid >> 3, eg = bid & 7;
    __shared__ float hs[HID_];
    hs[t] = h[b * HID_ + t];
    hs[t + 256] = h[b * HID_ + t + 256];
    __syncthreads();
    int e = eg * 64 + (t >> 2), ks = t & 3;
    const float4* wr = (const float4*)(Wh + (size_t)e * HID_ + ks * 128);
    const float* hp = &hs[ks * 128];
    float acc = 0.f;
#pragma unroll
    for (int i = 0; i < 32; ++i) {
        float4 w = wr[i];
        acc += w.x * hp[i*4] + w.y * hp[i*4+1] + w.z * hp[i*4+2] + w.w * hp[i*4+3];
    }
    acc += __shfl_xor(acc, 1, 64);
    acc += __shfl_xor(acc, 2, 64);
    if (ks == 0) gem[b * EMB_ + e] = acc + bh[e];
}

// ---- main conv-GEMM: BM=BN=256, BK=64, 8 waves (2x4), dbuf 128KiB LDS.
// Batch-stage 8 loads/iter + vmcnt(8) (full-iter latency cover), 32x32x16 MFMA.
#define MFMA32(a,b,c) __builtin_amdgcn_mfma_f32_32x32x16_bf16(a,b,c,0,0,0)

__global__ __launch_bounds__(512, 2) void k_conv(const __hip_bfloat16* __restrict__ pad,
                                                 const __hip_bfloat16* __restrict__ bt,
                                                 const float* __restrict__ gem,
                                                 const float* __restrict__ bconv,
                                                 const float* __restrict__ watt,
                                                 float* __restrict__ sp) {
    __shared__ __align__(16) char lds[131072];   // buf k: A at k*65536, B at +32768
    const int tid = threadIdx.x;
    const int lane = tid & 63, wid = tid >> 6;
    const int wm = wid >> 2, wn = wid & 3;        // 2 x 4 wave grid
    int bid0 = blockIdx.x;
    int bid = (bid0 & 7) * 64 + (bid0 >> 3);      // XCD chunked swizzle (512 % 8 == 0)
    const int tile_m = bid >> 1, tile_n = bid & 1;
    const int b = tile_m >> 1;

    // staging: LDS slot s holds logical (row, cbyte = (s&127) ^ ((row&7)<<4))
    int gA[4], gB[4];
#pragma unroll
    for (int i = 0; i < 4; ++i) {
        int s = i * 8192 + tid * 16;
        int row = s >> 7;
        int clocal = ((s & 127) ^ ((row & 7) << 4)) >> 1;
        int m = tile_m * 256 + row;
        int y = (m >> 6) & 7;
        int x = m & 63;
        gA[i] = ((b * PH + y) * PW + x) * C_ + clocal;   // tap (0,0) base
        int e = tile_n * 256 + row;
        gB[i] = e * C_ + clocal;
    }
    const int lsw = wid * 1024;

    const int la31 = lane & 31, hh = lane >> 5;
    const int xorv = (lane & 7) << 4;              // row&7 == lane&7 for all fragment rows

    f32x16 acc[4][2];
#pragma unroll
    for (int i = 0; i < 4; ++i)
#pragma unroll
        for (int j = 0; j < 2; ++j)
#pragma unroll
            for (int r = 0; r < 16; ++r) acc[i][j][r] = 0.f;

#define STAGE_A(i, nb, aofs) gload16(pad + gA[i] + (aofs), lds + (nb)*65536 + (i)*8192 + lsw)
#define STAGE_B(i, nb, bofs) gload16(bt + gB[i] + (bofs), lds + (nb)*65536 + 32768 + (i)*8192 + lsw)

    // prologue: stage K-tile 0 into buf 0
    STAGE_A(0, 0, 0); STAGE_A(1, 0, 0); STAGE_A(2, 0, 0); STAGE_A(3, 0, 0);
    STAGE_B(0, 0, 0); STAGE_B(1, 0, 0); STAGE_B(2, 0, 0); STAGE_B(3, 0, 0);

    for (int kt = 0; kt < 72; ++kt) {
        const int cur = kt & 1, nb = cur ^ 1;
        const char* bufA = lds + cur * 65536;
        const char* bufB = bufA + 32768;
        const int ktn = (kt < 71) ? kt + 1 : 71;   // last iter restages (never consumed)
        const int tapn = ktn >> 3;
        const int dyn_ = tapn / 3, dxn_ = tapn - dyn_ * 3;
        const int aofsn = (dyn_ * PW + dxn_) * C_ + ((ktn & 7) << 6);
        const int bofsn = tapn * (EMB_ * C_) + ((ktn & 7) << 6);

        // batch-issue all 8 next-tile loads (nb was freed by previous end-barrier)
        STAGE_A(0, nb, aofsn); STAGE_A(1, nb, aofsn);
        STAGE_A(2, nb, aofsn); STAGE_A(3, nb, aofsn);
        STAGE_B(0, nb, bofsn); STAGE_B(1, nb, bofsn);
        STAGE_B(2, nb, bofsn); STAGE_B(3, nb, bofsn);
        // 16 outstanding; drain the 8 oldest (= current tile), keep 8 in flight
        asm volatile("s_waitcnt vmcnt(8)" ::: "memory");
        __builtin_amdgcn_s_barrier();

#pragma unroll
        for (int kk = 0; kk < 4; ++kk) {
            const int cb = (kk * 32 + hh * 16) ^ xorv;
            short8 a0 = *(const short8*)(bufA + (wm * 128 +  0 + la31) * 128 + cb);
            short8 a1 = *(const short8*)(bufA + (wm * 128 + 32 + la31) * 128 + cb);
            short8 a2 = *(const short8*)(bufA + (wm * 128 + 64 + la31) * 128 + cb);
            short8 a3 = *(const short8*)(bufA + (wm * 128 + 96 + la31) * 128 + cb);
            short8 b0 = *(const short8*)(bufB + (wn * 64 +  0 + la31) * 128 + cb);
            short8 b1 = *(const short8*)(bufB + (wn * 64 + 32 + la31) * 128 + cb);
            __builtin_amdgcn_s_setprio(1);
            acc[0][0] = MFMA32(a0, b0, acc[0][0]);
            acc[0][1] = MFMA32(a0, b1, acc[0][1]);
            acc[1][0] = MFMA32(a1, b0, acc[1][0]);
            acc[1][1] = MFMA32(a1, b1, acc[1][1]);
            acc[2][0] = MFMA32(a2, b0, acc[2][0]);
            acc[2][1] = MFMA32(a2, b1, acc[2][1]);
            acc[3][0] = MFMA32(a3, b0, acc[3][0]);
            acc[3][1] = MFMA32(a3, b1, acc[3][1]);
            __builtin_amdgcn_s_setprio(0);
        }
        __builtin_amdgcn_s_barrier();
    }
    asm volatile("s_waitcnt vmcnt(0)" ::: "memory");

    // epilogue: 32x32 C/D layout: col=lane&31, row=(reg&3)+8*(reg>>2)+4*hh  [m74/m101]
    const int part = tile_n * 4 + wn;
    float addv[2], wv[2];
#pragma unroll
    for (int fn = 0; fn < 2; ++fn) {
        int e = tile_n * 256 + wn * 64 + fn * 32 + la31;
        addv[fn] = bconv[e] + gem[b * EMB_ + e];
        wv[fn] = watt[e];
    }
#pragma unroll
    for (int fm = 0; fm < 4; ++fm) {
        float sj[16];
#pragma unroll
        for (int r = 0; r < 16; ++r) sj[r] = 0.f;
#pragma unroll
        for (int fn = 0; fn < 2; ++fn)
#pragma unroll
            for (int r = 0; r < 16; ++r)
                sj[r] += fast_tanh(acc[fm][fn][r] + addv[fn]) * wv[fn];
#pragma unroll
        for (int mask = 1; mask < 32; mask <<= 1)
#pragma unroll
            for (int r = 0; r < 16; ++r)
                sj[r] += __shfl_xor(sj[r], mask, 64);
        if (la31 == 0) {
            int mbase = tile_m * 256 + wm * 128 + fm * 32 + hh * 4;
#pragma unroll
            for (int q = 0; q < 4; ++q)
                *(float4*)(sp + (size_t)part * M_ + mbase + q * 8) =
                    make_float4(sj[q*4], sj[q*4+1], sj[q*4+2], sj[q*4+3]);
        }
    }
}

// ---- softmax over L per batch -> alpha (written to d_out)
__global__ __launch_bounds__(512) void k_softmax(const float* __restrict__ sp,
                                                 const float* __restrict__ batt,
                                                 float* __restrict__ alpha) {
    int b = blockIdx.x, t = threadIdx.x;
    float s = batt[0];
#pragma unroll
    for (int p = 0; p < 8; ++p) s += sp[(size_t)p * M_ + b * L_ + t];
    int lane = t & 63, wid = t >> 6;
    __shared__ float red[8];
    float m = s;
#pragma unroll
    for (int mask = 1; mask < 64; mask <<= 1) m = fmaxf(m, __shfl_xor(m, mask, 64));
    if (lane == 0) red[wid] = m;
    __syncthreads();
    float M = red[0];
#pragma unroll
    for (int i = 1; i < 8; ++i) M = fmaxf(M, red[i]);
    float ev = __expf(s - M);
    float sum = ev;
#pragma unroll
    for (int mask = 1; mask < 64; mask <<= 1) sum += __shfl_xor(sum, mask, 64);
    __syncthreads();
    if (lane == 0) red[wid] = sum;
    __syncthreads();
    float S = 0.f;
#pragma unroll
    for (int i = 0; i < 8; ++i) S += red[i];
    alpha[b * L_ + t] = ev / S;
}

// ---- att_out[b,c] = sum_l alpha[b,l] * conv_f[b,c,l]
__global__ __launch_bounds__(256) void k_att(const float* __restrict__ cf,
                                             const float* __restrict__ alpha,
                                             float* __restrict__ att) {
    int bid = blockIdx.x;
    int b = bid >> 7, cg = bid & 127;
    int t = threadIdx.x, lane = t & 63, wid = t >> 6;
    int c = cg * 4 + wid;
    const float4* xr = (const float4*)(cf + (size_t)(b * C_ + c) * L_);
    const float4* ar = (const float4*)(alpha + b * L_);
    float acc = 0.f;
#pragma unroll
    for (int it = 0; it < 2; ++it) {
        float4 xv = xr[it * 64 + lane];
        float4 av = ar[it * 64 + lane];
        acc += xv.x * av.x + xv.y * av.y + xv.z * av.z + xv.w * av.w;
    }
#pragma unroll
    for (int mask = 1; mask < 64; mask <<= 1) acc += __shfl_xor(acc, mask, 64);
    if (lane == 0) att[b * C_ + c] = acc;
}

extern "C" void kernel_launch(void* const* d_in, const int* in_sizes, int n_in,
                              void* d_out, int out_size, void* d_ws, size_t ws_size,
                              hipStream_t stream) {
    const float* conv_f = (const float*)d_in[0];
    const float* h      = (const float*)d_in[1];
    const float* W_h    = (const float*)d_in[2];
    const float* b_h    = (const float*)d_in[3];
    const float* K_conv = (const float*)d_in[4];
    const float* b_conv = (const float*)d_in[5];
    const float* w_att  = (const float*)d_in[6];
    const float* b_att  = (const float*)d_in[7];
    float* out = (float*)d_out;              // [B*C] att_out then [B*L] alpha

    char* ws = (char*)d_ws;
    __hip_bfloat16* pad = (__hip_bfloat16*)ws;
    __hip_bfloat16* bt  = (__hip_bfloat16*)(ws + (size_t)PADSZ * 2);
    float* gem = (float*)(ws + (size_t)PADSZ * 2 + (size_t)BT_SZ * 2);
    float* sp  = gem + GEM_SZ;               // 8 * M_ floats

    k_pad<<<B_ * H_, 256, 0, stream>>>(conv_f, pad);
    k_wt<<<EMB_, 256, 0, stream>>>(K_conv, bt);
    k_gem<<<B_ * 8, 256, 0, stream>>>(h, W_h, b_h, gem);
    k_conv<<<512, 512, 0, stream>>>(pad, bt, gem, b_conv, w_att, sp);
    float* alpha = out + B_ * C_;
    k_softmax<<<B_, 512, 0, stream>>>(sp, b_att, alpha);
    k_att<<<B_ * C_ / 4, 256, 0, stream>>>(conv_f, alpha, out);
}

// Round 13
// 536.868 us; speedup vs baseline: 1.0186x; 1.0186x over previous
//
#include <hip/hip_runtime.h>
#include <hip/hip_bf16.h>
#include <stdint.h>

#define B_ 128
#define C_ 512
#define H_ 8
#define W_ 64
#define L_ 512
#define EMB_ 512
#define HID_ 512
#define M_ 65536
#define PH 10
#define PW 66
#define PADSZ (B_*PH*PW*C_)     /* bf16 elements */
#define BT_SZ (9*EMB_*C_)       /* bf16 elements */
#define GEM_SZ (B_*EMB_)        /* f32 */

typedef __attribute__((ext_vector_type(8))) short short8;
typedef __attribute__((ext_vector_type(4))) float f32x4;
typedef __attribute__((ext_vector_type(16))) float f32x16;

__device__ __forceinline__ void gload16(const void* g, void* l) {
    __builtin_amdgcn_global_load_lds(
        (const __attribute__((address_space(1))) unsigned int*)g,
        (__attribute__((address_space(3))) unsigned int*)l, 16, 0, 0);
}

__device__ __forceinline__ float fast_tanh(float x) {
    float e = __expf(2.0f * fabsf(x));
    float r = 1.0f - __fdividef(2.0f, e + 1.0f);
    return copysignf(r, x);
}

// ---- pad + transpose conv_f -> padded channel-last bf16 [B][PH][PW][C]; zeroes own halo
__global__ __launch_bounds__(256) void k_pad(const float* __restrict__ cf,
                                             __hip_bfloat16* __restrict__ pad) {
    int bid = blockIdx.x, t = threadIdx.x;
    int b = bid >> 3, y = bid & 7;
    for (int cc = 0; cc < 2; ++cc) {
        int c = cc * 256 + t;
        const float* src = cf + ((size_t)(b * C_ + c) * H_ + y) * W_;
        __hip_bfloat16* dst = pad + ((size_t)(b * PH + y + 1) * PW + 1) * C_ + c;
#pragma unroll
        for (int x = 0; x < W_; ++x)
            dst[(size_t)x * C_] = __float2bfloat16(src[x]);
    }
    // halo cols x=0, x=65 of row y+1
    __hip_bfloat16 z = __float2bfloat16(0.0f);
    for (int c = t; c < C_; c += 256) {
        pad[((size_t)(b * PH + y + 1) * PW + 0) * C_ + c] = z;
        pad[((size_t)(b * PH + y + 1) * PW + 65) * C_ + c] = z;
    }
    // halo rows 0 and 9 (uint stores, 2 bf16 each)
    if (y == 0) {
        unsigned int* r0 = (unsigned int*)(pad + (size_t)(b * PH + 0) * PW * C_);
        for (int i = t; i < PW * C_ / 2; i += 256) r0[i] = 0u;
    }
    if (y == 7) {
        unsigned int* r9 = (unsigned int*)(pad + (size_t)(b * PH + 9) * PW * C_);
        for (int i = t; i < PW * C_ / 2; i += 256) r9[i] = 0u;
    }
}

// ---- K_conv [EMB,C,3,3] f32 -> Bt [tap][e][c] bf16
__global__ __launch_bounds__(256) void k_wt(const float* __restrict__ kc,
                                            __hip_bfloat16* __restrict__ bt) {
    int e = blockIdx.x, t = threadIdx.x;
    for (int cc = 0; cc < 2; ++cc) {
        int c = cc * 256 + t;
        const float* src = kc + (size_t)(e * C_ + c) * 9;
#pragma unroll
        for (int tap = 0; tap < 9; ++tap)
            bt[(size_t)tap * EMB_ * C_ + e * C_ + c] = __float2bfloat16(src[tap]);
    }
}

// ---- g_em = h @ W_h^T + b_h (fp32), 1024 blocks, 4 threads per output
__global__ __launch_bounds__(256) void k_gem(const float* __restrict__ h,
                                             const float* __restrict__ Wh,
                                             const float* __restrict__ bh,
                                             float* __restrict__ gem) {
    int bid = blockIdx.x, t = threadIdx.x;
    int b = bid >> 3, eg = bid & 7;
    __shared__ float hs[HID_];
    hs[t] = h[b * HID_ + t];
    hs[t + 256] = h[b * HID_ + t + 256];
    __syncthreads();
    int e = eg * 64 + (t >> 2), ks = t & 3;
    const float4* wr = (const float4*)(Wh + (size_t)e * HID_ + ks * 128);
    const float* hp = &hs[ks * 128];
    float acc = 0.f;
#pragma unroll
    for (int i = 0; i < 32; ++i) {
        float4 w = wr[i];
        acc += w.x * hp[i*4] + w.y * hp[i*4+1] + w.z * hp[i*4+2] + w.w * hp[i*4+3];
    }
    acc += __shfl_xor(acc, 1, 64);
    acc += __shfl_xor(acc, 2, 64);
    if (ks == 0) gem[b * EMB_ + e] = acc + bh[e];
}

// ---- main conv-GEMM: BM=BN=256, BK=64, 8 waves (2x4), dbuf 128KiB LDS.
// 32x32x16 MFMA; staging spread across kk phases (R8 ledger: vmcnt(2), 2 loads/phase)
#define MFMA32(a,b,c) __builtin_amdgcn_mfma_f32_32x32x16_bf16(a,b,c,0,0,0)

__global__ __launch_bounds__(512, 2) void k_conv(const __hip_bfloat16* __restrict__ pad,
                                                 const __hip_bfloat16* __restrict__ bt,
                                                 const float* __restrict__ gem,
                                                 const float* __restrict__ bconv,
                                                 const float* __restrict__ watt,
                                                 float* __restrict__ sp) {
    __shared__ __align__(16) char lds[131072];   // buf k: A at k*65536, B at +32768
    const int tid = threadIdx.x;
    const int lane = tid & 63, wid = tid >> 6;
    const int wm = wid >> 2, wn = wid & 3;        // 2 x 4 wave grid
    int bid0 = blockIdx.x;
    int bid = (bid0 & 7) * 64 + (bid0 >> 3);      // XCD chunked swizzle (512 % 8 == 0)
    const int tile_m = bid >> 1, tile_n = bid & 1;
    const int b = tile_m >> 1;

    // staging: LDS slot s holds logical (row, cbyte = (s&127) ^ ((row&7)<<4))
    int gA[4], gB[4];
#pragma unroll
    for (int i = 0; i < 4; ++i) {
        int s = i * 8192 + tid * 16;
        int row = s >> 7;
        int clocal = ((s & 127) ^ ((row & 7) << 4)) >> 1;
        int m = tile_m * 256 + row;
        int y = (m >> 6) & 7;
        int x = m & 63;
        gA[i] = ((b * PH + y) * PW + x) * C_ + clocal;   // tap (0,0) base
        int e = tile_n * 256 + row;
        gB[i] = e * C_ + clocal;
    }
    const int lsw = wid * 1024;

    const int la31 = lane & 31, hh = lane >> 5;
    const int xorv = (lane & 7) << 4;              // row&7 == lane&7 for all fragment rows

    f32x16 acc[4][2];
#pragma unroll
    for (int i = 0; i < 4; ++i)
#pragma unroll
        for (int j = 0; j < 2; ++j)
#pragma unroll
            for (int r = 0; r < 16; ++r) acc[i][j][r] = 0.f;

#define STAGE_A(i, nb, aofs) gload16(pad + gA[i] + (aofs), lds + (nb)*65536 + (i)*8192 + lsw)
#define STAGE_B(i, nb, bofs) gload16(bt + gB[i] + (bofs), lds + (nb)*65536 + 32768 + (i)*8192 + lsw)

    // prologue: stage K-tile 0 into buf 0
    STAGE_A(0, 0, 0); STAGE_A(1, 0, 0); STAGE_A(2, 0, 0); STAGE_A(3, 0, 0);
    STAGE_B(0, 0, 0); STAGE_B(1, 0, 0); STAGE_B(2, 0, 0); STAGE_B(3, 0, 0);

    for (int kt = 0; kt < 72; ++kt) {
        const int cur = kt & 1, nb = cur ^ 1;
        const char* bufA = lds + cur * 65536;
        const char* bufB = bufA + 32768;
        const int ktn = (kt < 71) ? kt + 1 : 71;   // last iter restages (never consumed)
        const int tapn = ktn >> 3;
        const int dyn_ = tapn / 3, dxn_ = tapn - dyn_ * 3;
        const int aofsn = (dyn_ * PW + dxn_) * C_ + ((ktn & 7) << 6);
        const int bofsn = tapn * (EMB_ * C_) + ((ktn & 7) << 6);

        // R8-style spread staging: 2 loads now, 2 per kk phase below.
        STAGE_A(0, nb, aofsn); STAGE_A(1, nb, aofsn);
        // outstanding: 8 (cur tile) + 2 just issued; drain the 8, keep 2 in flight
        asm volatile("s_waitcnt vmcnt(2)" ::: "memory");
        __builtin_amdgcn_s_barrier();

#pragma unroll
        for (int kk = 0; kk < 4; ++kk) {
            if (kk == 1) { STAGE_A(2, nb, aofsn); STAGE_A(3, nb, aofsn); }
            if (kk == 2) { STAGE_B(0, nb, bofsn); STAGE_B(1, nb, bofsn); }
            if (kk == 3) { STAGE_B(2, nb, bofsn); STAGE_B(3, nb, bofsn); }
            const int cb = (kk * 32 + hh * 16) ^ xorv;
            short8 a0 = *(const short8*)(bufA + (wm * 128 +  0 + la31) * 128 + cb);
            short8 a1 = *(const short8*)(bufA + (wm * 128 + 32 + la31) * 128 + cb);
            short8 a2 = *(const short8*)(bufA + (wm * 128 + 64 + la31) * 128 + cb);
            short8 a3 = *(const short8*)(bufA + (wm * 128 + 96 + la31) * 128 + cb);
            short8 b0 = *(const short8*)(bufB + (wn * 64 +  0 + la31) * 128 + cb);
            short8 b1 = *(const short8*)(bufB + (wn * 64 + 32 + la31) * 128 + cb);
            __builtin_amdgcn_s_setprio(1);
            acc[0][0] = MFMA32(a0, b0, acc[0][0]);
            acc[0][1] = MFMA32(a0, b1, acc[0][1]);
            acc[1][0] = MFMA32(a1, b0, acc[1][0]);
            acc[1][1] = MFMA32(a1, b1, acc[1][1]);
            acc[2][0] = MFMA32(a2, b0, acc[2][0]);
            acc[2][1] = MFMA32(a2, b1, acc[2][1]);
            acc[3][0] = MFMA32(a3, b0, acc[3][0]);
            acc[3][1] = MFMA32(a3, b1, acc[3][1]);
            __builtin_amdgcn_s_setprio(0);
        }
        __builtin_amdgcn_s_barrier();
    }
    asm volatile("s_waitcnt vmcnt(0)" ::: "memory");

    // epilogue: 32x32 C/D layout: col=lane&31, row=(reg&3)+8*(reg>>2)+4*hh  [m74/m101]
    const int part = tile_n * 4 + wn;
    float addv[2], wv[2];
#pragma unroll
    for (int fn = 0; fn < 2; ++fn) {
        int e = tile_n * 256 + wn * 64 + fn * 32 + la31;
        addv[fn] = bconv[e] + gem[b * EMB_ + e];
        wv[fn] = watt[e];
    }
#pragma unroll
    for (int fm = 0; fm < 4; ++fm) {
        float sj[16];
#pragma unroll
        for (int r = 0; r < 16; ++r) sj[r] = 0.f;
#pragma unroll
        for (int fn = 0; fn < 2; ++fn)
#pragma unroll
            for (int r = 0; r < 16; ++r)
                sj[r] += fast_tanh(acc[fm][fn][r] + addv[fn]) * wv[fn];
#pragma unroll
        for (int mask = 1; mask < 32; mask <<= 1)
#pragma unroll
            for (int r = 0; r < 16; ++r)
                sj[r] += __shfl_xor(sj[r], mask, 64);
        if (la31 == 0) {
            int mbase = tile_m * 256 + wm * 128 + fm * 32 + hh * 4;
#pragma unroll
            for (int q = 0; q < 4; ++q)
                *(float4*)(sp + (size_t)part * M_ + mbase + q * 8) =
                    make_float4(sj[q*4], sj[q*4+1], sj[q*4+2], sj[q*4+3]);
        }
    }
}

// ---- softmax over L per batch -> alpha (written to d_out)
__global__ __launch_bounds__(512) void k_softmax(const float* __restrict__ sp,
                                                 const float* __restrict__ batt,
                                                 float* __restrict__ alpha) {
    int b = blockIdx.x, t = threadIdx.x;
    float s = batt[0];
#pragma unroll
    for (int p = 0; p < 8; ++p) s += sp[(size_t)p * M_ + b * L_ + t];
    int lane = t & 63, wid = t >> 6;
    __shared__ float red[8];
    float m = s;
#pragma unroll
    for (int mask = 1; mask < 64; mask <<= 1) m = fmaxf(m, __shfl_xor(m, mask, 64));
    if (lane == 0) red[wid] = m;
    __syncthreads();
    float M = red[0];
#pragma unroll
    for (int i = 1; i < 8; ++i) M = fmaxf(M, red[i]);
    float ev = __expf(s - M);
    float sum = ev;
#pragma unroll
    for (int mask = 1; mask < 64; mask <<= 1) sum += __shfl_xor(sum, mask, 64);
    __syncthreads();
    if (lane == 0) red[wid] = sum;
    __syncthreads();
    float S = 0.f;
#pragma unroll
    for (int i = 0; i < 8; ++i) S += red[i];
    alpha[b * L_ + t] = ev / S;
}

// ---- att_out[b,c] = sum_l alpha[b,l] * conv_f[b,c,l]
__global__ __launch_bounds__(256) void k_att(const float* __restrict__ cf,
                                             const float* __restrict__ alpha,
                                             float* __restrict__ att) {
    int bid = blockIdx.x;
    int b = bid >> 7, cg = bid & 127;
    int t = threadIdx.x, lane = t & 63, wid = t >> 6;
    int c = cg * 4 + wid;
    const float4* xr = (const float4*)(cf + (size_t)(b * C_ + c) * L_);
    const float4* ar = (const float4*)(alpha + b * L_);
    float acc = 0.f;
#pragma unroll
    for (int it = 0; it < 2; ++it) {
        float4 xv = xr[it * 64 + lane];
        float4 av = ar[it * 64 + lane];
        acc += xv.x * av.x + xv.y * av.y + xv.z * av.z + xv.w * av.w;
    }
#pragma unroll
    for (int mask = 1; mask < 64; mask <<= 1) acc += __shfl_xor(acc, mask, 64);
    if (lane == 0) att[b * C_ + c] = acc;
}

extern "C" void kernel_launch(void* const* d_in, const int* in_sizes, int n_in,
                              void* d_out, int out_size, void* d_ws, size_t ws_size,
                              hipStream_t stream) {
    const float* conv_f = (const float*)d_in[0];
    const float* h      = (const float*)d_in[1];
    const float* W_h    = (const float*)d_in[2];
    const float* b_h    = (const float*)d_in[3];
    const float* K_conv = (const float*)d_in[4];
    const float* b_conv = (const float*)d_in[5];
    const float* w_att  = (const float*)d_in[6];
    const float* b_att  = (const float*)d_in[7];
    float* out = (float*)d_out;              // [B*C] att_out then [B*L] alpha

    char* ws = (char*)d_ws;
    __hip_bfloat16* pad = (__hip_bfloat16*)ws;
    __hip_bfloat16* bt  = (__hip_bfloat16*)(ws + (size_t)PADSZ * 2);
    float* gem = (float*)(ws + (size_t)PADSZ * 2 + (size_t)BT_SZ * 2);
    float* sp  = gem + GEM_SZ;               // 8 * M_ floats

    k_pad<<<B_ * H_, 256, 0, stream>>>(conv_f, pad);
    k_wt<<<EMB_, 256, 0, stream>>>(K_conv, bt);
    k_gem<<<B_ * 8, 256, 0, stream>>>(h, W_h, b_h, gem);
    k_conv<<<512, 512, 0, stream>>>(pad, bt, gem, b_conv, w_att, sp);
    float* alpha = out + B_ * C_;
    k_softmax<<<B_, 512, 0, stream>>>(sp, b_att, alpha);
    k_att<<<B_ * C_ / 4, 256, 0, stream>>>(conv_f, alpha, out);
}